// Round 10
// baseline (30.372 us; speedup 1.0000x reference)
//
#include <hip/hip_runtime.h>
#include <hip/hip_bf16.h>
#include <math.h>

#define QN 128
#define SN 128
#define HN 32
#define CN (QN * SN)
#define TILE_R 256   // batch rows per block (4 M-tiles of 16 per wave)

using half8   = __attribute__((ext_vector_type(8))) _Float16;
using floatx4 = __attribute__((ext_vector_type(4))) float;

// Grouped-GEMM via MFMA, no LDS, no barriers. Block: 256 threads (4 waves),
// one q, 256 batch rows; wave w owns rows w*64..w*64+63 (four 16-row M-tiles).
// vs R9: TILE_R doubled 128->256 to amortize the W1 B-frag gather (64 scalar
// loads/thread, the dominant VMEM instruction cost) over 2x rows; epilogue
// moved inside the mt loop so only one acc[2] (8 VGPRs) is live at a time.
// A-frag lane(nA=lane&15, koct=lane>>4) holds X[row0+nA][kk*32+koct*8+i]:
// two float4 loads per frag, 16 rows x full 128B lines per instr pair.
__global__ __launch_bounds__(256, 4)
void divenc_kernel(const float* __restrict__ x,
                   const float* __restrict__ W1,
                   const float* __restrict__ b1,
                   const float* __restrict__ W2,
                   const float* __restrict__ b2,
                   float* __restrict__ out) {
  const int q    = blockIdx.x;
  const int b0   = blockIdx.y * TILE_R;
  const int tid  = threadIdx.x;
  const int lane = tid & 63;
  const int wid  = __builtin_amdgcn_readfirstlane(tid >> 6);
  const int nA   = lane & 15;   // n-col / A-row within tile
  const int koct = lane >> 4;   // k-octet 0..3

  // ---- B-frags: lane holds W1[q][kk*32+koct*8+i][n0*16+nA] as fp16.
  const float* __restrict__ w1q = W1 + (size_t)q * (SN * HN);
  half8 bf[2][4];
  #pragma unroll
  for (int n0 = 0; n0 < 2; ++n0) {
    #pragma unroll
    for (int kk = 0; kk < 4; ++kk) {
      #pragma unroll
      for (int i = 0; i < 8; ++i) {
        const int k = kk * 32 + koct * 8 + i;
        bf[n0][kk][i] = (_Float16)w1q[k * HN + n0 * 16 + nA];
      }
    }
  }

  const float b1a = b1[q * HN + nA],  b1b = b1[q * HN + 16 + nA];
  const float w2a = W2[q * HN + nA],  w2b = W2[q * HN + 16 + nA];
  const float b2q = b2[q];

  const int row0 = b0 + wid * 64;
  const floatx4 z = {0.f, 0.f, 0.f, 0.f};

  #pragma unroll
  for (int mt = 0; mt < 4; ++mt) {
    // ---- A-frags direct from global + MFMA (acc live only within this mt)
    floatx4 acc0 = z, acc1 = z;
    const float* __restrict__ rp =
        x + (size_t)(row0 + mt * 16 + nA) * CN + q * SN + koct * 8;
    #pragma unroll
    for (int kk = 0; kk < 4; ++kk) {
      const float4 va = *reinterpret_cast<const float4*>(rp + kk * 32);
      const float4 vb = *reinterpret_cast<const float4*>(rp + kk * 32 + 4);
      half8 af;
      af[0] = (_Float16)va.x; af[1] = (_Float16)va.y;
      af[2] = (_Float16)va.z; af[3] = (_Float16)va.w;
      af[4] = (_Float16)vb.x; af[5] = (_Float16)vb.y;
      af[6] = (_Float16)vb.z; af[7] = (_Float16)vb.w;
      acc0 = __builtin_amdgcn_mfma_f32_16x16x32_f16(af, bf[0][kk], acc0, 0, 0, 0);
      acc1 = __builtin_amdgcn_mfma_f32_16x16x32_f16(af, bf[1][kk], acc1, 0, 0, 0);
    }

    // ---- epilogue for this mt. C/D: col = nA, row(in tile) = koct*4 + reg.
    #pragma unroll
    for (int reg = 0; reg < 4; ++reg) {
      float v0 = acc0[reg] + b1a;
      v0 = v0 > 0.f ? v0 : expm1f(v0);
      float v1 = acc1[reg] + b1b;
      v1 = v1 > 0.f ? v1 : expm1f(v1);
      float t = fmaf(v0, w2a, v1 * w2b);
      t += __shfl_xor(t, 1);
      t += __shfl_xor(t, 2);
      t += __shfl_xor(t, 4);
      t += __shfl_xor(t, 8);
      if (nA == 0) {
        const int row = row0 + mt * 16 + koct * 4 + reg;
        out[(size_t)row * QN + q] = t + b2q;
      }
    }
  }
}

extern "C" void kernel_launch(void* const* d_in, const int* in_sizes, int n_in,
                              void* d_out, int out_size, void* d_ws, size_t ws_size,
                              hipStream_t stream) {
  const float* x  = (const float*)d_in[0];
  const float* W1 = (const float*)d_in[1];
  const float* b1 = (const float*)d_in[2];
  const float* W2 = (const float*)d_in[3];
  const float* b2 = (const float*)d_in[4];
  float* out = (float*)d_out;

  const int B = in_sizes[0] / CN;  // 2048
  dim3 grid(QN, B / TILE_R);
  divenc_kernel<<<grid, 256, 0, stream>>>(x, W1, b1, W2, b2, out);
}